// Round 7
// baseline (1419.192 us; speedup 1.0000x reference)
//
#include <hip/hip_runtime.h>
#include <hip/hip_bf16.h>
#include <hip/hip_cooperative_groups.h>
#include <cstdint>
#include <cstddef>

// ODE: dy/dt = tanh(y@W1+b1)@W2+b2.
// RK4: 7 steps h=0.2 + 1 step h=0.15 -> 32 flow evals; interior outputs via
// cubic Hermite dense output. ONE cooperative kernel, 256 blocks x 256 thr:
// per-eval ordering via device-scope flag counters (no grid-wide barriers in
// the main loop -> phases overlap across blocks). Split-K GEMM2 last-arriver
// does the RK4 combine inline (fixed read order -> deterministic).
// XCD-ownership mapping: XCD x owns N-slice x of both GEMMs -> weight slice
// + activations stay resident in that XCD's L2. Bounded spins (no hang),
// occupancy-gated multi-kernel fallback.

namespace cg = cooperative_groups;

#define GAS __attribute__((address_space(1)))
#define LAS __attribute__((address_space(3)))

typedef __bf16 bf16x8 __attribute__((ext_vector_type(8)));
typedef float  f32x4  __attribute__((ext_vector_type(4)));
typedef unsigned short u16;
typedef unsigned int   u32;

struct P {
  const float *x, *W1, *b1, *W2, *b2;
  float* out;
  u16 *W1t, *W2t, *ybf, *ytbf, *Abuf;  // Abuf: 2 parity buffers [512][4096]
  float *y, *part, *k1a, *k1b, *kb2, *kb3, *kb4;
  u32* flags;  // [0..31] f_abuf[m*4+quarter], [32..95] c_part[m*8+x], [96..103] f_state[m]
};

__device__ __forceinline__ u16 f2bf(float f) {
  __hip_bfloat16 h = __float2bfloat16(f);
  return __builtin_bit_cast(u16, h);
}

// ---- flag protocol (device scope; guide §6 G16) ----
__device__ __forceinline__ void signal(u32* f) {
  __threadfence();      // each thread: make my stores device-visible-ordered
  __syncthreads();      // all block stores fenced
  if (threadIdx.x == 0)
    __hip_atomic_fetch_add(f, 1u, __ATOMIC_RELEASE, __HIP_MEMORY_SCOPE_AGENT);
}
__device__ __forceinline__ void wait_ge(u32* f, u32 tgt) {
  if (threadIdx.x == 0) {
    int it = 0;
    while (__hip_atomic_load(f, __ATOMIC_RELAXED, __HIP_MEMORY_SCOPE_AGENT) < tgt
           && it < (1 << 22)) { __builtin_amdgcn_s_sleep(2); ++it; }  // bounded: no hang
  }
  __syncthreads();
  __threadfence();      // acquire side: invalidate stale L1/L2 before reads
}

// ---- transpose W[K][N] fp32 -> Wt[N][K] bf16 (256 thr, grid-stride 256) ----
__device__ void transpose_dev(const float* __restrict__ W, u16* __restrict__ Wt,
                              int K, int N, int bid, int tid, u16* s /*32*33*/) {
  const int ntk = K >> 5, ntiles = ntk * (N >> 5);
  const int tx = tid & 31, ty = tid >> 5;  // 32x8
  for (int t = bid; t < ntiles; t += 256) {
    int kb = (t % ntk) << 5, nb = (t / ntk) << 5;
    __syncthreads();
    #pragma unroll
    for (int i = 0; i < 32; i += 8)
      s[(ty + i) * 33 + tx] = f2bf(W[(size_t)(kb + ty + i) * N + nb + tx]);
    __syncthreads();
    #pragma unroll
    for (int i = 0; i < 32; i += 8)
      Wt[(size_t)(nb + ty + i) * K + kb + tx] = s[tx * 33 + ty + i];
  }
}

__device__ void do_setup(const P& p, int bid, int tid, u16* scratch) {
  transpose_dev(p.W1, p.W1t, 1024, 4096, bid, tid, scratch);
  transpose_dev(p.W2, p.W2t, 4096, 1024, bid, tid, scratch);
  const float4* x4 = (const float4*)p.x;
  #pragma unroll
  for (int r = 0; r < 2; ++r) {
    int i = bid * 512 + r * 256 + tid;
    float4 v = x4[i];
    ((float4*)p.y)[i] = v;
    ((float4*)p.out)[i] = v;
    ((ushort4*)p.ybf)[i] = make_ushort4(f2bf(v.x), f2bf(v.y), f2bf(v.z), f2bf(v.w));
  }
}

// ---- stage one (A 64x64, B 128x64) bf16 tile pair; XOR-swizzled source ----
__device__ __forceinline__ void stage(const u16* __restrict__ A,
                                      const u16* __restrict__ Bt,
                                      char* AsB, char* BsB,
                                      int m0, int n0, int kt, int K, int tid) {
  #pragma unroll
  for (int i = 0; i < 2; ++i) {
    int j = i * 256 + tid;
    int row = j >> 3, slot = j & 7, kc = slot ^ (row & 7);
    __builtin_amdgcn_global_load_lds(
        (const GAS void*)(A + (size_t)(m0 + row) * K + kt + kc * 8),
        (LAS void*)(AsB + j * 16), 16, 0, 0);
  }
  #pragma unroll
  for (int i = 0; i < 4; ++i) {
    int j = i * 256 + tid;
    int row = j >> 3, slot = j & 7, kc = slot ^ (row & 7);
    __builtin_amdgcn_global_load_lds(
        (const GAS void*)(Bt + (size_t)(n0 + row) * K + kt + kc * 8),
        (LAS void*)(BsB + j * 16), 16, 0, 0);
  }
}

// ---- GEMM tile core: C(64x128) = A[64 rows m0..][K] @ Bt[128 rows n0..][K]^T,
//      K-chunk [k0, k0+1024), 4 waves 2x2, wave tile 32x64, dbuf LDS. ----
// TANH=1: Cbf[(m0+r)*ldC + n0+c] = bf16(tanh(acc + bias[n0+c]))
// TANH=0: Cf[r*128 + c] = acc   (compact partial tile)
template<int TANH>
__device__ void tileK(const u16* __restrict__ A, const u16* __restrict__ Bt,
                      const float* __restrict__ bias, u16* __restrict__ Cbf,
                      float* __restrict__ Cf, int K, int ldC,
                      int m0, int n0, int k0,
                      u16 (*As)[4096], u16 (*Bs)[8192], int tid) {
  const int lane = tid & 63, wid = tid >> 6;
  const int wr = wid >> 1, wc = wid & 1, lrow = lane & 15, kgrp = lane >> 4;

  f32x4 acc[2][4];
  #pragma unroll
  for (int mi = 0; mi < 2; ++mi)
    #pragma unroll
    for (int ni = 0; ni < 4; ++ni) acc[mi][ni] = (f32x4){0.f, 0.f, 0.f, 0.f};

  stage(A, Bt, (char*)As[0], (char*)Bs[0], m0, n0, k0, K, tid);
  __syncthreads();
  int cur = 0;
  for (int t = 0; t < 16; ++t) {
    if (t + 1 < 16)
      stage(A, Bt, (char*)As[cur ^ 1], (char*)Bs[cur ^ 1],
            m0, n0, k0 + (t + 1) * 64, K, tid);
    const char* AsB = (const char*)As[cur];
    const char* BsB = (const char*)Bs[cur];
    #pragma unroll
    for (int ks = 0; ks < 2; ++ks) {
      bf16x8 af[2], bfr[4];
      #pragma unroll
      for (int mi = 0; mi < 2; ++mi) {
        int row = wr * 32 + mi * 16 + lrow;
        int slot = (ks * 4 + kgrp) ^ (row & 7);
        af[mi] = *(const bf16x8*)(AsB + row * 128 + slot * 16);
      }
      #pragma unroll
      for (int ni = 0; ni < 4; ++ni) {
        int row = wc * 64 + ni * 16 + lrow;
        int slot = (ks * 4 + kgrp) ^ (row & 7);
        bfr[ni] = *(const bf16x8*)(BsB + row * 128 + slot * 16);
      }
      #pragma unroll
      for (int mi = 0; mi < 2; ++mi)
        #pragma unroll
        for (int ni = 0; ni < 4; ++ni)
          acc[mi][ni] = __builtin_amdgcn_mfma_f32_16x16x32_bf16(
              af[mi], bfr[ni], acc[mi][ni], 0, 0, 0);
    }
    __syncthreads();
    cur ^= 1;
  }

  // C/D layout: col = lane&15, row = (lane>>4)*4 + reg (m89)
  #pragma unroll
  for (int mi = 0; mi < 2; ++mi) {
    #pragma unroll
    for (int ni = 0; ni < 4; ++ni) {
      int pcol = wc * 64 + ni * 16 + lrow;
      #pragma unroll
      for (int r = 0; r < 4; ++r) {
        int prow = wr * 32 + mi * 16 + kgrp * 4 + r;
        float v = acc[mi][ni][r];
        if (TANH) {
          v = tanhf(v + bias[n0 + pcol]);
          Cbf[(size_t)(m0 + prow) * ldC + n0 + pcol] = f2bf(v);
        } else {
          Cf[prow * 128 + pcol] = v;
        }
      }
    }
  }
}

// ---- combine patch (m, x): F = sum_g part + b2; RK4 algebra; Hermite on e==1 ----
__device__ void do_combine(const P& p, int m, int x, int n, int e, int tid) {
  const int q = 131072;  // float4s per [512x1024]
  const float h = (n < 7) ? 0.2f : 0.15f;
  const float h6 = h / 6.f;
  const float coef = (e == 3) ? h : h * 0.5f;
  float* k1buf = (n & 1) ? p.k1b : p.k1a;
  const float* k1prev = (n & 1) ? p.k1a : p.k1b;
  const float4 hc0 = {0.84375f, 0.028125f, 0.15625f, -0.009375f};
  const float4 hc1 = {0.5f,     0.025f,    0.5f,     -0.025f};
  const float4 hc2 = {0.15625f, 0.009375f, 0.84375f, -0.028125f};
  const float4* p4  = (const float4*)p.part;
  const float4* b24 = (const float4*)p.b2;
  const size_t pb = (size_t)(m * 8 + x) * 8192;

  #pragma unroll
  for (int r = 0; r < 8; ++r) {
    int i4 = r * 256 + tid;
    int row = i4 >> 5, col4 = i4 & 31;
    int gi = (64 * m + row) * 256 + 32 * x + col4;
    float4 s0 = p4[pb + i4], s1 = p4[pb + 2048 + i4],
           s2 = p4[pb + 4096 + i4], s3 = p4[pb + 6144 + i4];
    float4 bb = b24[32 * x + col4];
    float4 F;
    F.x = s0.x + s1.x + s2.x + s3.x + bb.x;
    F.y = s0.y + s1.y + s2.y + s3.y + bb.y;
    F.z = s0.z + s1.z + s2.z + s3.z + bb.z;
    F.w = s0.w + s1.w + s2.w + s3.w + bb.w;
    float4 yv = ((const float4*)p.y)[gi];
    float4 nv;
    if (e < 4) {
      float* kbuf = (e == 1) ? k1buf : (e == 2 ? p.kb2 : p.kb3);
      ((float4*)kbuf)[gi] = F;
      nv.x = yv.x + coef * F.x;
      nv.y = yv.y + coef * F.y;
      nv.z = yv.z + coef * F.z;
      nv.w = yv.w + coef * F.w;
      ((ushort4*)p.ytbf)[gi] =
          make_ushort4(f2bf(nv.x), f2bf(nv.y), f2bf(nv.z), f2bf(nv.w));
      if (e == 1 && n >= 1) {  // Hermite for interval n-1, f1 = F
        float4* o4 = (float4*)p.out;
        float4 A_ = o4[(size_t)(4 * (n - 1)) * q + gi];
        float4 B_ = o4[(size_t)(4 * n) * q + gi];
        float4 C_ = ((const float4*)k1prev)[gi];
        float4 o;
        o.x = hc0.x * A_.x + hc0.y * C_.x + hc0.z * B_.x + hc0.w * F.x;
        o.y = hc0.x * A_.y + hc0.y * C_.y + hc0.z * B_.y + hc0.w * F.y;
        o.z = hc0.x * A_.z + hc0.y * C_.z + hc0.z * B_.z + hc0.w * F.z;
        o.w = hc0.x * A_.w + hc0.y * C_.w + hc0.z * B_.w + hc0.w * F.w;
        o4[(size_t)(4 * (n - 1) + 1) * q + gi] = o;
        o.x = hc1.x * A_.x + hc1.y * C_.x + hc1.z * B_.x + hc1.w * F.x;
        o.y = hc1.x * A_.y + hc1.y * C_.y + hc1.z * B_.y + hc1.w * F.y;
        o.z = hc1.x * A_.z + hc1.y * C_.z + hc1.z * B_.z + hc1.w * F.z;
        o.w = hc1.x * A_.w + hc1.y * C_.w + hc1.z * B_.w + hc1.w * F.w;
        o4[(size_t)(4 * (n - 1) + 2) * q + gi] = o;
        o.x = hc2.x * A_.x + hc2.y * C_.x + hc2.z * B_.x + hc2.w * F.x;
        o.y = hc2.x * A_.y + hc2.y * C_.y + hc2.z * B_.y + hc2.w * F.y;
        o.z = hc2.x * A_.z + hc2.y * C_.z + hc2.z * B_.z + hc2.w * F.z;
        o.w = hc2.x * A_.w + hc2.y * C_.w + hc2.z * B_.w + hc2.w * F.w;
        o4[(size_t)(4 * (n - 1) + 3) * q + gi] = o;
      }
    } else {
      if (n == 7) ((float4*)p.kb4)[gi] = F;
      float4 a = ((const float4*)k1buf)[gi];
      float4 c = ((const float4*)p.kb2)[gi];
      float4 d = ((const float4*)p.kb3)[gi];
      nv.x = yv.x + h6 * (a.x + 2.f * c.x + 2.f * d.x + F.x);
      nv.y = yv.y + h6 * (a.y + 2.f * c.y + 2.f * d.y + F.y);
      nv.z = yv.z + h6 * (a.z + 2.f * c.z + 2.f * d.z + F.z);
      nv.w = yv.w + h6 * (a.w + 2.f * c.w + 2.f * d.w + F.w);
      ((float4*)p.y)[gi] = nv;
      int outIdx = (n < 7) ? 4 * (n + 1) : 31;
      ((float4*)p.out)[(size_t)outIdx * q + gi] = nv;
      ((ushort4*)p.ybf)[gi] =
          make_ushort4(f2bf(nv.x), f2bf(nv.y), f2bf(nv.z), f2bf(nv.w));
    }
  }
}

// tail Hermite: [out28, out31], h=0.15, theta=1/3,2/3; f0=k1b, f1=kb4
__device__ void do_tail(const P& p, int bid, int tid) {
  const int q = 131072;
  const float4 tc0 = {0.7407407f, 0.0222222f, 0.2592593f, -0.0111111f};
  const float4 tc1 = {0.2592593f, 0.0111111f, 0.7407407f, -0.0222222f};
  float4* o4 = (float4*)p.out;
  #pragma unroll
  for (int r = 0; r < 2; ++r) {
    int i = bid * 512 + r * 256 + tid;
    float4 A_ = o4[(size_t)28 * q + i];
    float4 B_ = o4[(size_t)31 * q + i];
    float4 C_ = ((const float4*)p.k1b)[i];
    float4 D_ = ((const float4*)p.kb4)[i];
    float4 o;
    o.x = tc0.x * A_.x + tc0.y * C_.x + tc0.z * B_.x + tc0.w * D_.x;
    o.y = tc0.x * A_.y + tc0.y * C_.y + tc0.z * B_.y + tc0.w * D_.y;
    o.z = tc0.x * A_.z + tc0.y * C_.z + tc0.z * B_.z + tc0.w * D_.z;
    o.w = tc0.x * A_.w + tc0.y * C_.w + tc0.z * B_.w + tc0.w * D_.w;
    o4[(size_t)29 * q + i] = o;
    o.x = tc1.x * A_.x + tc1.y * C_.x + tc1.z * B_.x + tc1.w * D_.x;
    o.y = tc1.x * A_.y + tc1.y * C_.y + tc1.z * B_.y + tc1.w * D_.y;
    o.z = tc1.x * A_.z + tc1.y * C_.z + tc1.z * B_.z + tc1.w * D_.z;
    o.w = tc1.x * A_.w + tc1.y * C_.w + tc1.z * B_.w + tc1.w * D_.w;
    o4[(size_t)30 * q + i] = o;
  }
}

// ---------------- fused cooperative kernel ----------------
__global__ __launch_bounds__(256, 1) void ode_fused(P p) {
  __shared__ __attribute__((aligned(16))) u16 As[2][4096];
  __shared__ __attribute__((aligned(16))) u16 Bs[2][8192];
  __shared__ int lastsh;
  cg::grid_group grid = cg::this_grid();
  const int tid = threadIdx.x, bid = blockIdx.x;

  if (bid == 0 && tid < 128) p.flags[tid] = 0;  // before grid.sync
  do_setup(p, bid, tid, (u16*)As[0]);
  grid.sync();

  // roles: XCD x = bid&7 owns N-slice x of both GEMMs (dispatch round-robin)
  const int xcd = bid & 7, jj = bid >> 3, m = jj & 7, g = jj >> 3;
  const int nt1 = 4 * xcd + g;      // GEMM1 N-tile (BN=128, 32 tiles)
  const int q1 = nt1 >> 3;          // which Abuf K-quarter this tile feeds
  u32* f_abuf  = p.flags;           // [m*4+quarter]: +8 per eval
  u32* c_part  = p.flags + 32;      // [m*8+x]: +4 per eval; last does combine
  u32* f_state = p.flags + 96;      // [m]: +8 per eval

  for (int ev = 1; ev <= 32; ++ev) {
    const int n = (ev - 1) >> 2, e = ((ev - 1) & 3) + 1;
    const u16* st = (e == 1) ? p.ybf : p.ytbf;
    if (ev > 1) wait_ge(&f_state[m], 8u * (ev - 1));
    u16* ab = p.Abuf + (size_t)(ev & 1) * 2097152;  // parity dbuf [512][4096]
    tileK<1>(st, p.W1t, p.b1, ab, nullptr, 1024, 4096,
             64 * m, 128 * nt1, 0, As, Bs, tid);
    signal(&f_abuf[m * 4 + q1]);
    wait_ge(&f_abuf[m * 4 + g], 8u * ev);
    tileK<0>(ab, p.W2t, nullptr, nullptr,
             p.part + (size_t)((m * 8 + xcd) * 4 + g) * 8192,
             4096, 128, 64 * m, 128 * xcd, 1024 * g, As, Bs, tid);
    __threadfence();
    __syncthreads();
    if (tid == 0) {
      u32 old = __hip_atomic_fetch_add(&c_part[m * 8 + xcd], 1u,
                                       __ATOMIC_ACQ_REL, __HIP_MEMORY_SCOPE_AGENT);
      lastsh = (old == 4u * ev - 1u);
    }
    __syncthreads();
    if (lastsh) {  // block-uniform
      __threadfence();  // acquire: siblings' part stores
      do_combine(p, m, xcd, n, e, tid);
      signal(&f_state[m]);
    }
  }
  grid.sync();
  do_tail(p, bid, tid);
}

// ---------------- fallback multi-kernel path (same device code) ----------------
__global__ __launch_bounds__(256) void setup_k(P p) {
  __shared__ u16 s[1056];
  do_setup(p, blockIdx.x, threadIdx.x, s);
}
__global__ __launch_bounds__(256) void g1_k(P p, int ev) {
  __shared__ __attribute__((aligned(16))) u16 As[2][4096];
  __shared__ __attribute__((aligned(16))) u16 Bs[2][8192];
  const int bid = blockIdx.x, tid = threadIdx.x;
  const int xcd = bid & 7, jj = bid >> 3, m = jj & 7, g = jj >> 3;
  const int e = ((ev - 1) & 3) + 1;
  const u16* st = (e == 1) ? p.ybf : p.ytbf;
  u16* ab = p.Abuf + (size_t)(ev & 1) * 2097152;
  tileK<1>(st, p.W1t, p.b1, ab, nullptr, 1024, 4096,
           64 * m, 128 * (4 * xcd + g), 0, As, Bs, tid);
}
__global__ __launch_bounds__(256) void g2_k(P p, int ev) {
  __shared__ __attribute__((aligned(16))) u16 As[2][4096];
  __shared__ __attribute__((aligned(16))) u16 Bs[2][8192];
  const int bid = blockIdx.x, tid = threadIdx.x;
  const int xcd = bid & 7, jj = bid >> 3, m = jj & 7, g = jj >> 3;
  u16* ab = p.Abuf + (size_t)(ev & 1) * 2097152;
  tileK<0>(ab, p.W2t, nullptr, nullptr,
           p.part + (size_t)((m * 8 + xcd) * 4 + g) * 8192,
           4096, 128, 64 * m, 128 * xcd, 1024 * g, As, Bs, tid);
}
__global__ __launch_bounds__(256) void comb_k(P p, int ev) {
  const int b = blockIdx.x;  // 64 blocks: patch (m=b>>3, x=b&7)
  const int n = (ev - 1) >> 2, e = ((ev - 1) & 3) + 1;
  do_combine(p, b >> 3, b & 7, n, e, threadIdx.x);
}
__global__ __launch_bounds__(256) void tail_k(P p) {
  do_tail(p, blockIdx.x, threadIdx.x);
}

extern "C" void kernel_launch(void* const* d_in, const int* in_sizes, int n_in,
                              void* d_out, int out_size, void* d_ws, size_t ws_size,
                              hipStream_t stream) {
  P p;
  p.x  = (const float*)d_in[0];
  p.W1 = (const float*)d_in[1];
  p.b1 = (const float*)d_in[2];
  p.W2 = (const float*)d_in[3];
  p.b2 = (const float*)d_in[4];
  p.out = (float*)d_out;

  const int Dq = 1024, Hq = 4096;
  const int MN = 512 * 1024;
  char* ws = (char*)d_ws;
  size_t off = 0;
  p.W1t  = (u16*)(ws + off);   off += (size_t)Hq * Dq * 2;       // 8 MB
  p.W2t  = (u16*)(ws + off);   off += (size_t)Dq * Hq * 2;       // 8 MB
  p.y    = (float*)(ws + off); off += (size_t)MN * 4;            // 2 MB
  p.ybf  = (u16*)(ws + off);   off += (size_t)MN * 2;            // 1 MB
  p.ytbf = (u16*)(ws + off);   off += (size_t)MN * 2;            // 1 MB
  p.Abuf = (u16*)(ws + off);   off += (size_t)2 * 512 * Hq * 2;  // 8 MB (parity dbuf)
  p.part = (float*)(ws + off); off += (size_t)2097152 * 4;       // 8 MB
  p.k1a  = (float*)(ws + off); off += (size_t)MN * 4;
  p.k1b  = (float*)(ws + off); off += (size_t)MN * 4;
  p.kb2  = (float*)(ws + off); off += (size_t)MN * 4;
  p.kb3  = (float*)(ws + off); off += (size_t)MN * 4;
  p.kb4  = (float*)(ws + off); off += (size_t)MN * 4;
  p.flags = (u32*)(ws + off);  off += 4096;
  if (ws_size < off) return;

  int dev = 0;
  (void)hipGetDevice(&dev);
  int numCU = 0;
  (void)hipDeviceGetAttribute(&numCU, hipDeviceAttributeMultiprocessorCount, dev);
  int maxb = 0;
  (void)hipOccupancyMaxActiveBlocksPerMultiprocessor(&maxb, ode_fused, 256, 0);

  hipError_t st = hipErrorUnknown;
  if (maxb > 0 && (long)maxb * numCU >= 256) {
    void* args[] = {&p};
    st = hipLaunchCooperativeKernel((void*)ode_fused, dim3(256), dim3(256),
                                    args, 0, stream);
  }
  if (st != hipSuccess) {
    setup_k<<<256, 256, 0, stream>>>(p);
    for (int ev = 1; ev <= 32; ++ev) {
      g1_k<<<256, 256, 0, stream>>>(p, ev);
      g2_k<<<256, 256, 0, stream>>>(p, ev);
      comb_k<<<64, 256, 0, stream>>>(p, ev);
    }
    tail_k<<<256, 256, 0, stream>>>(p);
  }
}